// Round 1
// baseline (242.962 us; speedup 1.0000x reference)
//
#include <hip/hip_runtime.h>
#include <stdint.h>

#define BSH (32 * 128 * 128)

typedef __attribute__((ext_vector_type(8))) __bf16 bf16x8;
typedef __attribute__((ext_vector_type(4))) float f32x4;

__device__ __forceinline__ unsigned short f2bf(float f) {
  union { float f; unsigned u; } v; v.f = f;
  return (unsigned short)((v.u + 0x7FFFu + ((v.u >> 16) & 1u)) >> 16);
}

#if __has_builtin(__builtin_amdgcn_exp2f)
#define EXP2F(x) __builtin_amdgcn_exp2f(x)
#else
#define EXP2F(x) exp2f(x)
#endif
#if __has_builtin(__builtin_amdgcn_rcpf)
#define RCPF(x) __builtin_amdgcn_rcpf(x)
#else
#define RCPF(x) (1.0f / (x))
#endif

// tanh-form GELU: g = y - y/(1 + e^{2*0.79788456*(y + 0.044715 y^3)})
// max abs error vs exact erf-GELU ~3e-3 -- well within 9.25e-2 tolerance.
__device__ __forceinline__ float gelu_f(float y) {
  float u = y * y;
  float p = __builtin_fmaf(u, 0.044715f, 1.0f) * y;
  float w = EXP2F(p * 2.30220787f);  // 2 * 0.7978845608 * log2(e)
  return y - y * RCPF(1.0f + w);
}

// async 16B/lane global->LDS. LDS side: wave-uniform base + lane*16 (m104).
// Global side: per-lane gather address (this is how we realize the XOR swizzle).
__device__ __forceinline__ void gl_lds16(const void* g, void* l) {
  __builtin_amdgcn_global_load_lds((__attribute__((address_space(1))) void*)(g),
                                   (__attribute__((address_space(3))) void*)(l),
                                   16, 0, 0);
}

// ---------------------------------------------------------------------------
// Prepass: bf16-convert + transpose 128x128 blocks.
//   blocks 0..255   : W1[i][j][s][t]   -> W1T[i][j][t][s]
//   blocks 256..287 : trend2[b][s][h]  -> T2T[b][h][s]   (+ fp32 copy to out2)
//   block 288/289   : Wm1/Wm2[in][out] -> WmT[out][in]
// ---------------------------------------------------------------------------
__device__ __forceinline__ void transpose_block(const float* __restrict__ src,
                                                unsigned short* __restrict__ dst,
                                                unsigned short* lds) {
  const int tid = threadIdx.x;
  const float4* s4 = (const float4*)src;
#pragma unroll
  for (int it = 0; it < 16; ++it) {
    int i4 = tid + it * 256;
    float4 v = s4[i4];
    int s = i4 >> 5;
    int t = (i4 * 4) & 127;
    unsigned short* p = lds + s * 130 + t;  // pitch 130: 2-way (free) bank pattern
    p[0] = f2bf(v.x); p[1] = f2bf(v.y); p[2] = f2bf(v.z); p[3] = f2bf(v.w);
  }
  __syncthreads();
#pragma unroll
  for (int it = 0; it < 8; ++it) {
    int c = tid + it * 256;
    int tr = c >> 4, sc = c & 15;
    unsigned short tmp[8] __attribute__((aligned(16)));
#pragma unroll
    for (int e = 0; e < 8; ++e) tmp[e] = lds[(sc * 8 + e) * 130 + tr];
    *(uint4*)(dst + tr * 128 + sc * 8) = *(const uint4*)tmp;
  }
}

__global__ __launch_bounds__(256) void prepass_kernel(
    const float* __restrict__ W1, const float* __restrict__ trend2,
    const float* __restrict__ Wm1, const float* __restrict__ Wm2,
    unsigned short* __restrict__ W1T, unsigned short* __restrict__ T2T,
    unsigned short* __restrict__ Wm1T, unsigned short* __restrict__ Wm2T,
    float* __restrict__ out2) {
  __shared__ unsigned short lds[128 * 130];
  const int bid = blockIdx.x;
  if (bid < 256) {
    transpose_block(W1 + bid * 16384, W1T + bid * 16384, lds);
  } else if (bid < 288) {
    const int b = bid - 256;
    transpose_block(trend2 + b * 16384, T2T + b * 16384, lds);
    const float4* s4 = (const float4*)(trend2 + b * 16384);
    float4* d4 = (float4*)(out2 + b * 16384);
#pragma unroll
    for (int it = 0; it < 16; ++it)
      d4[threadIdx.x + it * 256] = s4[threadIdx.x + it * 256];
  } else if (bid == 288) {
    transpose_block(Wm1, Wm1T, lds);
  } else {
    transpose_block(Wm2, Wm2T, lds);
  }
}

// ---------------------------------------------------------------------------
// Mix kernel: one block per (j, b). Computes, fused in-register:
//   Y[h,t] = sum_s XT[b,h,s] * W1T[j,t,s]          (MFMA 16x16x32 bf16)
//   res[h] = sum_t gelu(Y[h,t] + b1[j,t]) * W2[j,t]
//   xout[b,j,h] = bf16( trend[b,j,h] + res[h] + b2[j] )
// Triangular skip: only n-tiles/k-steps covering <=j are computed (exact:
// W1/b1/W2 are zero-masked beyond the prefix).
// LDS chunk swizzle: chunk(m,k16) = m*16 + (k16 ^ (m&15)) -- realized by
// per-lane gather on the global side of global_load_lds; makes frag
// ds_read_b128 2-way bank aliased (free) instead of 16-way.
// ---------------------------------------------------------------------------
__global__ __launch_bounds__(256) void mix_kernel(
    const unsigned short* __restrict__ XT,   // [32][128][128] bf16 [b][h][s]
    const unsigned short* __restrict__ W1T,  // [128][128][128] bf16 [j][t][s]
    const float* __restrict__ b1,            // [128][128] [j][t]
    const float* __restrict__ W2,            // [128][128] [j][t]
    const float* __restrict__ b2,            // [128]
    const float* __restrict__ trend,         // [32][128][128] fp32 [b][s][h]
    unsigned short* __restrict__ xout) {     // [32][128][128] bf16 [b][j][h]
  __shared__ unsigned short lds_a[128 * 128];
  __shared__ unsigned short lds_b[128 * 128];
  __shared__ float res2[2][128];

  const int bid = blockIdx.x;
  const int j = bid >> 5;        // j-major: consecutive blocks share W1T[j] in L2
  const int b = bid & 31;
  const int tid = threadIdx.x;
  const int wave = tid >> 6;
  const int lane = tid & 63;
  const int wm = wave >> 1;
  const int wn = wave & 1;
  const int lane15 = lane & 15;
  const int quad = lane >> 4;

  const int ntiles = (j >> 4) + 1;  // n-tiles containing t<=j
  const int ksteps = (j >> 5) + 1;  // k-steps containing s<=j

  {
    const unsigned short* Xb = XT + b * 16384;
    const unsigned short* Wj = W1T + j * 16384;
    for (int q = wave; q < 32; q += 4) {          // A: full 128 rows
      int m = q * 4 + quad;
      gl_lds16(Xb + m * 128 + ((lane15 ^ (m & 15)) << 3), lds_a + q * 512);
    }
    const int nq = ntiles * 4;
    for (int q = wave; q < nq; q += 4) {          // B: only needed rows
      int n = q * 4 + quad;
      gl_lds16(Wj + n * 128 + ((lane15 ^ (n & 15)) << 3), lds_b + q * 512);
    }
  }
  __syncthreads();

  int n_act = ntiles - wn * 4;
  n_act = n_act < 0 ? 0 : (n_act > 4 ? 4 : n_act);

  f32x4 acc[4][4];
#pragma unroll
  for (int mi = 0; mi < 4; ++mi)
#pragma unroll
    for (int ni = 0; ni < 4; ++ni) {
      f32x4 z = {0.f, 0.f, 0.f, 0.f};
      acc[mi][ni] = z;
    }

  const bf16x8* Av = (const bf16x8*)lds_a;
  const bf16x8* Bv = (const bf16x8*)lds_b;

  for (int ks = 0; ks < ksteps; ++ks) {
    const int kq = ks * 4 + quad;
    bf16x8 af[4], bfr[4];
#pragma unroll
    for (int mi = 0; mi < 4; ++mi) {
      int m = wm * 64 + mi * 16 + lane15;
      af[mi] = Av[m * 16 + (kq ^ lane15)];
    }
#pragma unroll
    for (int ni = 0; ni < 4; ++ni)
      if (ni < n_act) {
        int n = wn * 64 + ni * 16 + lane15;
        bfr[ni] = Bv[n * 16 + (kq ^ lane15)];
      }
#pragma unroll
    for (int ni = 0; ni < 4; ++ni)
      if (ni < n_act) {
#pragma unroll
        for (int mi = 0; mi < 4; ++mi)
          acc[mi][ni] = __builtin_amdgcn_mfma_f32_16x16x32_bf16(
              af[mi], bfr[ni], acc[mi][ni], 0, 0, 0);
      }
  }

  float b1v[4], w2v[4];
#pragma unroll
  for (int ni = 0; ni < 4; ++ni) {
    b1v[ni] = 0.f; w2v[ni] = 0.f;
    if (ni < n_act) {
      int t = wn * 64 + ni * 16 + lane15;
      b1v[ni] = b1[j * 128 + t];
      w2v[ni] = W2[j * 128 + t];
    }
  }

#pragma unroll
  for (int mi = 0; mi < 4; ++mi) {
#pragma unroll
    for (int r = 0; r < 4; ++r) {
      float p = 0.f;
#pragma unroll
      for (int ni = 0; ni < 4; ++ni)
        if (ni < n_act) {
          float y = acc[mi][ni][r] + b1v[ni];
          p += gelu_f(y) * w2v[ni];
        }
      // reduce over the 16 t-columns held by the 16 lanes of this group
      p += __shfl_xor(p, 1, 16);
      p += __shfl_xor(p, 2, 16);
      p += __shfl_xor(p, 4, 16);
      p += __shfl_xor(p, 8, 16);
      if (lane15 == 0) res2[wn][wm * 64 + mi * 16 + quad * 4 + r] = p;
    }
  }
  __syncthreads();

  if (tid < 128) {
    float v = res2[0][tid] + res2[1][tid] + b2[j] +
              trend[b * 16384 + j * 128 + tid];
    xout[b * 16384 + j * 128 + tid] = f2bf(v);
  }
}

// ---------------------------------------------------------------------------
// MLP kernel: one block per b. out = gelu(x @ Wm1 + bm1) @ Wm2 + bm2.
// Writes fp32 result to outf; if write_t, also bf16-transposed [b][h][s]
// (needed as the A-operand of the next mix stage).
// ---------------------------------------------------------------------------
__global__ __launch_bounds__(256) void mlp_kernel(
    const unsigned short* __restrict__ Xin,   // [32][128][128] bf16 [b][s][h]
    const unsigned short* __restrict__ Wm1T,  // [128][128] bf16 [out][in]
    const unsigned short* __restrict__ Wm2T,  // [128][128] bf16 [out][in]
    const float* __restrict__ bm1,
    const float* __restrict__ bm2,
    float* __restrict__ outf,                 // [32][128][128] fp32
    unsigned short* __restrict__ outT,        // [32][128][128] bf16 [b][h][s]
    const int write_t) {
  __shared__ unsigned short lds_x[128 * 130];  // staging (chunks), later transpose tile
  __shared__ unsigned short lds_w1[128 * 128];
  __shared__ unsigned short lds_w2[128 * 128];
  __shared__ unsigned short lds_u[128 * 128];

  const int b = blockIdx.x;
  const int tid = threadIdx.x;
  const int wave = tid >> 6;
  const int lane = tid & 63;
  const int wm = wave >> 1;
  const int wn = wave & 1;
  const int lane15 = lane & 15;
  const int quad = lane >> 4;

  {
    const unsigned short* Xb = Xin + b * 16384;
    for (int q = wave; q < 32; q += 4) {
      int m = q * 4 + quad;
      gl_lds16(Xb + m * 128 + ((lane15 ^ (m & 15)) << 3), lds_x + q * 512);
    }
    for (int q = wave; q < 32; q += 4) {
      int n = q * 4 + quad;
      gl_lds16(Wm1T + n * 128 + ((lane15 ^ (n & 15)) << 3), lds_w1 + q * 512);
      gl_lds16(Wm2T + n * 128 + ((lane15 ^ (n & 15)) << 3), lds_w2 + q * 512);
    }
  }
  __syncthreads();

  f32x4 acc[4][4];
#pragma unroll
  for (int mi = 0; mi < 4; ++mi)
#pragma unroll
    for (int ni = 0; ni < 4; ++ni) {
      f32x4 z = {0.f, 0.f, 0.f, 0.f};
      acc[mi][ni] = z;
    }

  {  // GEMM1: x @ Wm1
    const bf16x8* Av = (const bf16x8*)lds_x;
    const bf16x8* Bv = (const bf16x8*)lds_w1;
#pragma unroll
    for (int ks = 0; ks < 4; ++ks) {
      const int kq = ks * 4 + quad;
      bf16x8 af[4], bfr[4];
#pragma unroll
      for (int mi = 0; mi < 4; ++mi)
        af[mi] = Av[(wm * 64 + mi * 16 + lane15) * 16 + (kq ^ lane15)];
#pragma unroll
      for (int ni = 0; ni < 4; ++ni)
        bfr[ni] = Bv[(wn * 64 + ni * 16 + lane15) * 16 + (kq ^ lane15)];
#pragma unroll
      for (int ni = 0; ni < 4; ++ni)
#pragma unroll
        for (int mi = 0; mi < 4; ++mi)
          acc[mi][ni] = __builtin_amdgcn_mfma_f32_16x16x32_bf16(
              af[mi], bfr[ni], acc[mi][ni], 0, 0, 0);
    }
  }

  {  // bias + gelu -> lds_u (swizzled A-operand layout for GEMM2)
    float bv[4];
#pragma unroll
    for (int ni = 0; ni < 4; ++ni) bv[ni] = bm1[wn * 64 + ni * 16 + lane15];
#pragma unroll
    for (int mi = 0; mi < 4; ++mi)
#pragma unroll
      for (int ni = 0; ni < 4; ++ni)
#pragma unroll
        for (int r = 0; r < 4; ++r) {
          int m = wm * 64 + mi * 16 + quad * 4 + r;
          int k = wn * 64 + ni * 16 + lane15;
          float g = gelu_f(acc[mi][ni][r] + bv[ni]);
          lds_u[((m * 16 + ((k >> 3) ^ (m & 15))) << 3) | (k & 7)] = f2bf(g);
        }
  }
  __syncthreads();

#pragma unroll
  for (int mi = 0; mi < 4; ++mi)
#pragma unroll
    for (int ni = 0; ni < 4; ++ni) {
      f32x4 z = {0.f, 0.f, 0.f, 0.f};
      acc[mi][ni] = z;
    }

  {  // GEMM2: u @ Wm2
    const bf16x8* Av = (const bf16x8*)lds_u;
    const bf16x8* Bv = (const bf16x8*)lds_w2;
#pragma unroll
    for (int ks = 0; ks < 4; ++ks) {
      const int kq = ks * 4 + quad;
      bf16x8 af[4], bfr[4];
#pragma unroll
      for (int mi = 0; mi < 4; ++mi)
        af[mi] = Av[(wm * 64 + mi * 16 + lane15) * 16 + (kq ^ lane15)];
#pragma unroll
      for (int ni = 0; ni < 4; ++ni)
        bfr[ni] = Bv[(wn * 64 + ni * 16 + lane15) * 16 + (kq ^ lane15)];
#pragma unroll
      for (int ni = 0; ni < 4; ++ni)
#pragma unroll
        for (int mi = 0; mi < 4; ++mi)
          acc[mi][ni] = __builtin_amdgcn_mfma_f32_16x16x32_bf16(
              af[mi], bfr[ni], acc[mi][ni], 0, 0, 0);
    }
  }

  {  // epilogue: fp32 out + optional bf16 tile for transpose
    float bv[4];
#pragma unroll
    for (int ni = 0; ni < 4; ++ni) bv[ni] = bm2[wn * 64 + ni * 16 + lane15];
#pragma unroll
    for (int mi = 0; mi < 4; ++mi)
#pragma unroll
      for (int ni = 0; ni < 4; ++ni)
#pragma unroll
        for (int r = 0; r < 4; ++r) {
          int m = wm * 64 + mi * 16 + quad * 4 + r;
          int n = wn * 64 + ni * 16 + lane15;
          float v = acc[mi][ni][r] + bv[ni];
          outf[b * 16384 + m * 128 + n] = v;
          if (write_t) lds_x[m * 130 + n] = f2bf(v);
        }
  }

  if (write_t) {
    __syncthreads();
#pragma unroll
    for (int it = 0; it < 8; ++it) {
      int c = tid + it * 256;
      int h = c >> 4, sc = c & 15;
      unsigned short tmp[8] __attribute__((aligned(16)));
#pragma unroll
      for (int e = 0; e < 8; ++e) tmp[e] = lds_x[(sc * 8 + e) * 130 + h];
      *(uint4*)(outT + b * 16384 + h * 128 + sc * 8) = *(const uint4*)tmp;
    }
  }
}

// ---------------------------------------------------------------------------
extern "C" void kernel_launch(void* const* d_in, const int* in_sizes, int n_in,
                              void* d_out, int out_size, void* d_ws, size_t ws_size,
                              hipStream_t stream) {
  (void)in_sizes; (void)n_in; (void)out_size; (void)ws_size;
  const float* trend0 = (const float*)d_in[0];
  const float* trend1 = (const float*)d_in[1];
  const float* trend2 = (const float*)d_in[2];
  const float* W1  = (const float*)d_in[3];
  const float* b1  = (const float*)d_in[4];
  const float* W2  = (const float*)d_in[5];
  const float* b2  = (const float*)d_in[6];
  const float* Wm1 = (const float*)d_in[7];
  const float* bm1 = (const float*)d_in[8];
  const float* Wm2 = (const float*)d_in[9];
  const float* bm2 = (const float*)d_in[10];
  float* out = (float*)d_out;
  char* ws = (char*)d_ws;

  unsigned short* W1T  = (unsigned short*)(ws);                 // 8 MB
  unsigned short* T2T  = (unsigned short*)(ws + 8388608);       // 1 MB
  unsigned short* x1   = (unsigned short*)(ws + 9437184);       // 1 MB
  unsigned short* A1T  = (unsigned short*)(ws + 10485760);      // 1 MB
  unsigned short* x2   = (unsigned short*)(ws + 11534336);      // 1 MB
  unsigned short* Wm1T = (unsigned short*)(ws + 12582912);      // 32 KB
  unsigned short* Wm2T = (unsigned short*)(ws + 12615680);      // 32 KB

  // outputs: [A2 | A1 | trend2]
  prepass_kernel<<<290, 256, 0, stream>>>(W1, trend2, Wm1, Wm2,
                                          W1T, T2T, Wm1T, Wm2T, out + 2 * BSH);
  // stage i=0: X = trend2, residual = trend1
  mix_kernel<<<4096, 256, 0, stream>>>(T2T, W1T, b1, W2, b2, trend1, x1);
  // A1 = mlp(x1) -> d_out[1], + transposed bf16 for next mix
  mlp_kernel<<<32, 256, 0, stream>>>(x1, Wm1T, Wm2T, bm1, bm2,
                                     out + BSH, A1T, 1);
  // stage i=1: X = A1, residual = trend0
  mix_kernel<<<4096, 256, 0, stream>>>(A1T, W1T + 128 * 16384, b1 + 16384,
                                       W2 + 16384, b2 + 128, trend0, x2);
  // A2 = mlp(x2) -> d_out[0]
  mlp_kernel<<<32, 256, 0, stream>>>(x2, Wm1T, Wm2T, bm1, bm2,
                                     out, (unsigned short*)nullptr, 0);
}

// Round 2
// 155.522 us; speedup vs baseline: 1.5622x; 1.5622x over previous
//
#include <hip/hip_runtime.h>
#include <stdint.h>

#define BSH (32 * 128 * 128)

typedef __attribute__((ext_vector_type(8))) __bf16 bf16x8;
typedef __attribute__((ext_vector_type(4))) float f32x4;

__device__ __forceinline__ unsigned short f2bf(float f) {
  union { float f; unsigned u; } v; v.f = f;
  return (unsigned short)((v.u + 0x7FFFu + ((v.u >> 16) & 1u)) >> 16);
}

// Guaranteed single-instruction transcendentals (round-1 suspect: libm
// exp2f + precise divide blew the gelu up to ~25 VALU instrs).
__device__ __forceinline__ float fast_exp2(float x) {
#if __has_builtin(__builtin_amdgcn_exp2f)
  return __builtin_amdgcn_exp2f(x);
#else
  float r; asm("v_exp_f32 %0, %1" : "=v"(r) : "v"(x)); return r;
#endif
}
__device__ __forceinline__ float fast_rcp(float x) {
#if __has_builtin(__builtin_amdgcn_rcpf)
  return __builtin_amdgcn_rcpf(x);
#else
  float r; asm("v_rcp_f32 %0, %1" : "=v"(r) : "v"(x)); return r;
#endif
}

// tanh-form GELU via exp2/rcp: ~9 VALU (2 quarter-rate). Same math as the
// round-1 kernel that passed at absmax 3.9e-3.
__device__ __forceinline__ float gelu_f(float y) {
  float u = y * y;
  float p = __builtin_fmaf(u, 0.044715f, 1.0f) * y;
  float w = fast_exp2(p * 2.30220787f);  // 2 * 0.7978845608 * log2(e)
  return y - y * fast_rcp(1.0f + w);
}

// ---------------------------------------------------------------------------
// Chunked k-major layout: tensor [row][k] (k contiguous) is stored as chunks
// chunk(kq, row) = base + (kq*128 + row)*8 bf16  (16 B per chunk, kq = k>>3).
// An MFMA fragment read (lane15 = row-within-tile, quad = kq-within-kstep)
// then hits 256 B contiguous per quad -> one global_load_dwordx4, perfectly
// segmented, L2-resident. No LDS staging anywhere in the GEMMs.
// ---------------------------------------------------------------------------

// Prepass: fp32 -> bf16 chunked-transpose of 128x128 blocks.
__device__ __forceinline__ void transpose_block_c(const float* __restrict__ src,
                                                  unsigned short* __restrict__ dst,
                                                  unsigned short* lds) {
  const int tid = threadIdx.x;
  const float4* s4 = (const float4*)src;
#pragma unroll
  for (int it = 0; it < 16; ++it) {
    int i4 = tid + it * 256;
    float4 v = s4[i4];
    int s = i4 >> 5;
    int t = (i4 * 4) & 127;
    unsigned short* p = lds + s * 130 + t;  // pitch 130: conflict-light
    p[0] = f2bf(v.x); p[1] = f2bf(v.y); p[2] = f2bf(v.z); p[3] = f2bf(v.w);
  }
  __syncthreads();
#pragma unroll
  for (int it = 0; it < 8; ++it) {
    int c = tid + it * 256;
    int tr = c >> 4, sc = c & 15;  // tr = transposed row (t/h/out), sc = k-chunk
    unsigned short tmp[8] __attribute__((aligned(16)));
#pragma unroll
    for (int e = 0; e < 8; ++e) tmp[e] = lds[(sc * 8 + e) * 130 + tr];
    *(uint4*)(dst + (sc * 128 + tr) * 8) = *(const uint4*)tmp;
  }
}

__global__ __launch_bounds__(256) void prepass_kernel(
    const float* __restrict__ W1, const float* __restrict__ trend2,
    const float* __restrict__ Wm1, const float* __restrict__ Wm2,
    unsigned short* __restrict__ W1Tc, unsigned short* __restrict__ T2c,
    unsigned short* __restrict__ Wm1c, unsigned short* __restrict__ Wm2c,
    float* __restrict__ out2) {
  __shared__ unsigned short lds[128 * 130];
  const int bid = blockIdx.x;
  if (bid < 256) {               // W1[i][j][s][t] -> chunks (kq_s, t)
    transpose_block_c(W1 + bid * 16384, W1Tc + bid * 16384, lds);
  } else if (bid < 288) {        // trend2[b][s][h] -> chunks (kq_s, h)
    const int b = bid - 256;
    transpose_block_c(trend2 + b * 16384, T2c + b * 16384, lds);
    const float4* s4 = (const float4*)(trend2 + b * 16384);
    float4* d4 = (float4*)(out2 + b * 16384);
#pragma unroll
    for (int it = 0; it < 16; ++it)
      d4[threadIdx.x + it * 256] = s4[threadIdx.x + it * 256];
  } else if (bid == 288) {       // Wm[in][out] -> chunks (kq_in, out)
    transpose_block_c(Wm1, Wm1c, lds);
  } else {
    transpose_block_c(Wm2, Wm2c, lds);
  }
}

// ---------------------------------------------------------------------------
// Mix kernel v2: one block per (j,b). M = t (A = W1Tc[j]), N = h (B = XTc[b]),
// K = s. All fragments loaded straight from L2-resident chunked global
// tensors; LDS = 1 KB reduction scratch only -> 4 blocks/CU.
// 2 passes over h-halves keep acc at 32 VGPR. Triangular skip: m-tiles
// (t) limited to ntiles, k-steps to ksteps (exact: zero-masked W1/b1/W2).
// Epilogue: res[h] = sum_t gelu(Y[t,h]+b1[t])*W2[t]; with t = rows, the
// reduce is in-register fmas + 2 shfl_xor (quads) + LDS combine (waves).
// ---------------------------------------------------------------------------
__global__ __launch_bounds__(256, 4) void mix_kernel(
    const unsigned short* __restrict__ XTc,   // [32] chunks (kq_s, h)
    const unsigned short* __restrict__ W1Tc,  // [128] chunks (kq_s, t) this stage
    const float* __restrict__ b1,             // [128][128] (j, t)
    const float* __restrict__ W2,             // [128][128] (j, t)
    const float* __restrict__ b2,             // [128]
    const float* __restrict__ trend,          // [32][128][128] fp32
    unsigned short* __restrict__ xoutc) {     // [32] chunks (kq_h, j)
  __shared__ float res_ws[4][64];
  const int bid = blockIdx.x;
  const int j = bid >> 5;   // consecutive blocks share W1Tc[j] in L2
  const int b = bid & 31;
  const int tid = threadIdx.x;
  const int wave = tid >> 6;
  const int lane = tid & 63;
  const int lane15 = lane & 15;
  const int quad = lane >> 4;

  const int ntiles = (j >> 4) + 1;  // t-tiles with t <= j
  const int ksteps = (j >> 5) + 1;  // k 32-steps with s <= j
  const bool act0 = wave < ntiles;        // this wave's m-tile #0 = wave
  const bool act1 = wave + 4 < ntiles;    // m-tile #1 = wave + 4

  const unsigned short* Aj = XTc ? W1Tc + j * 16384 : W1Tc;
  const unsigned short* Bb = XTc + b * 16384;

  float4 b1v0 = {0, 0, 0, 0}, w2v0 = {0, 0, 0, 0};
  float4 b1v1 = {0, 0, 0, 0}, w2v1 = {0, 0, 0, 0};
  if (act0) {
    int tb = wave * 16 + quad * 4;
    b1v0 = *(const float4*)(b1 + j * 128 + tb);
    w2v0 = *(const float4*)(W2 + j * 128 + tb);
  }
  if (act1) {
    int tb = (wave + 4) * 16 + quad * 4;
    b1v1 = *(const float4*)(b1 + j * 128 + tb);
    w2v1 = *(const float4*)(W2 + j * 128 + tb);
  }

#pragma unroll
  for (int p = 0; p < 2; ++p) {
    f32x4 acc0[4], acc1[4];
#pragma unroll
    for (int ni = 0; ni < 4; ++ni) {
      f32x4 z = {0.f, 0.f, 0.f, 0.f};
      acc0[ni] = z; acc1[ni] = z;
    }
    if (act0) {
      for (int ks = 0; ks < ksteps; ++ks) {
        const int kq = ks * 4 + quad;
        bf16x8 bfr[4];
#pragma unroll
        for (int ni = 0; ni < 4; ++ni)
          bfr[ni] = *(const bf16x8*)(Bb + (kq * 128 + p * 64 + ni * 16 + lane15) * 8);
        bf16x8 a0 = *(const bf16x8*)(Aj + (kq * 128 + wave * 16 + lane15) * 8);
        if (act1) {
          bf16x8 a1 = *(const bf16x8*)(Aj + (kq * 128 + (wave + 4) * 16 + lane15) * 8);
#pragma unroll
          for (int ni = 0; ni < 4; ++ni) {
            acc0[ni] = __builtin_amdgcn_mfma_f32_16x16x32_bf16(a0, bfr[ni], acc0[ni], 0, 0, 0);
            acc1[ni] = __builtin_amdgcn_mfma_f32_16x16x32_bf16(a1, bfr[ni], acc1[ni], 0, 0, 0);
          }
        } else {
#pragma unroll
          for (int ni = 0; ni < 4; ++ni)
            acc0[ni] = __builtin_amdgcn_mfma_f32_16x16x32_bf16(a0, bfr[ni], acc0[ni], 0, 0, 0);
        }
      }
    }
    float psum[4] = {0.f, 0.f, 0.f, 0.f};
    if (act0) {
#pragma unroll
      for (int ni = 0; ni < 4; ++ni) {
#pragma unroll
        for (int r = 0; r < 4; ++r) {
          float y = acc0[ni][r] + ((const float*)&b1v0)[r];
          psum[ni] += gelu_f(y) * ((const float*)&w2v0)[r];
        }
        if (act1) {
#pragma unroll
          for (int r = 0; r < 4; ++r) {
            float y = acc1[ni][r] + ((const float*)&b1v1)[r];
            psum[ni] += gelu_f(y) * ((const float*)&w2v1)[r];
          }
        }
      }
    }
#pragma unroll
    for (int ni = 0; ni < 4; ++ni) {  // sum over quads (t-rows across lanes)
      psum[ni] += __shfl_xor(psum[ni], 16, 64);
      psum[ni] += __shfl_xor(psum[ni], 32, 64);
    }
    res_ws[wave][quad * 16 + lane15] = psum[quad];
    __syncthreads();
    if (tid < 64) {
      int h = p * 64 + tid;
      float v = res_ws[0][tid] + res_ws[1][tid] + res_ws[2][tid] + res_ws[3][tid]
              + b2[j] + trend[b * 16384 + j * 128 + h];
      // write chunked (kq_h, j) so the MLP can frag-load it directly
      xoutc[b * 16384 + ((h >> 3) * 128 + j) * 8 + (h & 7)] = f2bf(v);
    }
    __syncthreads();  // res_ws reused by next pass
  }
}

// ---------------------------------------------------------------------------
// MLP kernel v2: grid 128 = 32 b x 4 m-blocks of 32 rows. A/W fragments from
// chunked global (L2); only the GEMM1->GEMM2 bounce (U) and the output
// transpose tile live in LDS (~17 KB).
// ---------------------------------------------------------------------------
__global__ __launch_bounds__(256, 4) void mlp_kernel(
    const unsigned short* __restrict__ Xc,    // [32] chunks (kq_h, j)
    const unsigned short* __restrict__ Wm1c,  // chunks (kq_in, out)
    const unsigned short* __restrict__ Wm2c,
    const float* __restrict__ bm1,
    const float* __restrict__ bm2,
    float* __restrict__ outf,                 // [32][128][128] fp32
    unsigned short* __restrict__ outTc,       // [32] chunks (kq_s, h), optional
    const int write_t) {
  __shared__ __align__(16) unsigned short U[4096];   // chunks (kq_h2, jr) 32-row pitch
  __shared__ unsigned short ldsT[32 * 132];          // transpose tile, pitch 132
  const int bid = blockIdx.x;
  const int b = bid >> 2;
  const int mb = bid & 3;
  const int tid = threadIdx.x;
  const int wave = tid >> 6;
  const int lane = tid & 63;
  const int lane15 = lane & 15;
  const int quad = lane >> 4;
  const int m16 = wave & 1;   // which 16-row tile of the 32
  const int nh = wave >> 1;   // which 64-col half

  const unsigned short* Xb = Xc + b * 16384;

  f32x4 acc[4];
#pragma unroll
  for (int ni = 0; ni < 4; ++ni) { f32x4 z = {0.f, 0.f, 0.f, 0.f}; acc[ni] = z; }
#pragma unroll
  for (int ks = 0; ks < 4; ++ks) {  // GEMM1: x @ Wm1
    int kq = ks * 4 + quad;
    bf16x8 a = *(const bf16x8*)(Xb + (kq * 128 + mb * 32 + m16 * 16 + lane15) * 8);
    bf16x8 w[4];
#pragma unroll
    for (int ni = 0; ni < 4; ++ni)
      w[ni] = *(const bf16x8*)(Wm1c + (kq * 128 + nh * 64 + ni * 16 + lane15) * 8);
#pragma unroll
    for (int ni = 0; ni < 4; ++ni)
      acc[ni] = __builtin_amdgcn_mfma_f32_16x16x32_bf16(a, w[ni], acc[ni], 0, 0, 0);
  }
#pragma unroll
  for (int ni = 0; ni < 4; ++ni) {  // bias+gelu -> U (A-layout for GEMM2)
    int n = nh * 64 + ni * 16 + lane15;
    float bv = bm1[n];
    int co = (n >> 3) * 32;
    int el = n & 7;
#pragma unroll
    for (int r = 0; r < 4; ++r) {
      int jr = m16 * 16 + quad * 4 + r;
      U[(co + jr) * 8 + el] = f2bf(gelu_f(acc[ni][r] + bv));
    }
  }
  __syncthreads();
#pragma unroll
  for (int ni = 0; ni < 4; ++ni) { f32x4 z = {0.f, 0.f, 0.f, 0.f}; acc[ni] = z; }
#pragma unroll
  for (int ks = 0; ks < 4; ++ks) {  // GEMM2: u @ Wm2
    int kq = ks * 4 + quad;
    bf16x8 a = *(const bf16x8*)(U + (kq * 32 + m16 * 16 + lane15) * 8);
    bf16x8 w[4];
#pragma unroll
    for (int ni = 0; ni < 4; ++ni)
      w[ni] = *(const bf16x8*)(Wm2c + (kq * 128 + nh * 64 + ni * 16 + lane15) * 8);
#pragma unroll
    for (int ni = 0; ni < 4; ++ni)
      acc[ni] = __builtin_amdgcn_mfma_f32_16x16x32_bf16(a, w[ni], acc[ni], 0, 0, 0);
  }
  {
    float* outb = outf + b * 16384 + mb * 32 * 128;
#pragma unroll
    for (int ni = 0; ni < 4; ++ni) {
      int n = nh * 64 + ni * 16 + lane15;
      float bv = bm2[n];
#pragma unroll
      for (int r = 0; r < 4; ++r) {
        int jr = m16 * 16 + quad * 4 + r;
        float v = acc[ni][r] + bv;
        outb[jr * 128 + n] = v;
        if (write_t) ldsT[jr * 132 + n] = f2bf(v);
      }
    }
  }
  if (write_t) {  // emit chunked (kq_s, h) for the next mix stage's B-operand
    __syncthreads();
#pragma unroll
    for (int it = 0; it < 2; ++it) {
      int c = tid + it * 256;
      int h = c & 127, jr8 = c >> 7;
      unsigned short tmp[8] __attribute__((aligned(16)));
#pragma unroll
      for (int e = 0; e < 8; ++e) tmp[e] = ldsT[(jr8 * 8 + e) * 132 + h];
      *(uint4*)(outTc + b * 16384 + ((mb * 4 + jr8) * 128 + h) * 8) = *(const uint4*)tmp;
    }
  }
}

// ---------------------------------------------------------------------------
extern "C" void kernel_launch(void* const* d_in, const int* in_sizes, int n_in,
                              void* d_out, int out_size, void* d_ws, size_t ws_size,
                              hipStream_t stream) {
  (void)in_sizes; (void)n_in; (void)out_size; (void)ws_size;
  const float* trend0 = (const float*)d_in[0];
  const float* trend1 = (const float*)d_in[1];
  const float* trend2 = (const float*)d_in[2];
  const float* W1  = (const float*)d_in[3];
  const float* b1  = (const float*)d_in[4];
  const float* W2  = (const float*)d_in[5];
  const float* b2  = (const float*)d_in[6];
  const float* Wm1 = (const float*)d_in[7];
  const float* bm1 = (const float*)d_in[8];
  const float* Wm2 = (const float*)d_in[9];
  const float* bm2 = (const float*)d_in[10];
  float* out = (float*)d_out;
  char* ws = (char*)d_ws;

  unsigned short* W1Tc = (unsigned short*)(ws);             // 8 MB
  unsigned short* T2c  = (unsigned short*)(ws + 8388608);   // 1 MB
  unsigned short* x1c  = (unsigned short*)(ws + 9437184);   // 1 MB
  unsigned short* A1Tc = (unsigned short*)(ws + 10485760);  // 1 MB
  unsigned short* x2c  = (unsigned short*)(ws + 11534336);  // 1 MB
  unsigned short* Wm1c = (unsigned short*)(ws + 12582912);  // 32 KB
  unsigned short* Wm2c = (unsigned short*)(ws + 12615680);  // 32 KB

  // outputs: [A2 | A1 | trend2]
  prepass_kernel<<<290, 256, 0, stream>>>(W1, trend2, Wm1, Wm2,
                                          W1Tc, T2c, Wm1c, Wm2c, out + 2 * BSH);
  // stage i=0: X = trend2, residual = trend1
  mix_kernel<<<4096, 256, 0, stream>>>(T2c, W1Tc, b1, W2, b2, trend1, x1c);
  // A1 = mlp(x1) -> d_out[1] (+ chunked transpose for the next mix stage)
  mlp_kernel<<<128, 256, 0, stream>>>(x1c, Wm1c, Wm2c, bm1, bm2,
                                      out + BSH, A1Tc, 1);
  // stage i=1: X = A1, residual = trend0
  mix_kernel<<<4096, 256, 0, stream>>>(A1Tc, W1Tc + 128 * 16384, b1 + 16384,
                                       W2 + 16384, b2 + 128, trend0, x2c);
  // A2 = mlp(x2) -> d_out[0]
  mlp_kernel<<<128, 256, 0, stream>>>(x2c, Wm1c, Wm2c, bm1, bm2,
                                      out, (unsigned short*)nullptr, 0);
}

// Round 3
// 146.513 us; speedup vs baseline: 1.6583x; 1.0615x over previous
//
#include <hip/hip_runtime.h>
#include <stdint.h>

#define BSH (32 * 128 * 128)

typedef __attribute__((ext_vector_type(8))) __bf16 bf16x8;
typedef __attribute__((ext_vector_type(4))) float f32x4;

__device__ __forceinline__ unsigned short f2bf(float f) {
  union { float f; unsigned u; } v; v.f = f;
  return (unsigned short)((v.u + 0x7FFFu + ((v.u >> 16) & 1u)) >> 16);
}

__device__ __forceinline__ float fast_exp2(float x) {
#if __has_builtin(__builtin_amdgcn_exp2f)
  return __builtin_amdgcn_exp2f(x);
#else
  float r; asm("v_exp_f32 %0, %1" : "=v"(r) : "v"(x)); return r;
#endif
}
__device__ __forceinline__ float fast_rcp(float x) {
#if __has_builtin(__builtin_amdgcn_rcpf)
  return __builtin_amdgcn_rcpf(x);
#else
  float r; asm("v_rcp_f32 %0, %1" : "=v"(r) : "v"(x)); return r;
#endif
}

// tanh-form GELU (used in the cheap MLP path; ~3e-3 max err vs exact).
__device__ __forceinline__ float gelu_f(float y) {
  float u = y * y;
  float p = __builtin_fmaf(u, 0.044715f, 1.0f) * y;
  float w = fast_exp2(p * 2.30220787f);
  return y - y * fast_rcp(1.0f + w);
}

// ---------------------------------------------------------------------------
// Chunked k-major layout: tensor [row][k] stored as chunk(kq,row) =
// base + (kq*128 + row)*8 bf16 (16 B). MFMA fragment read = one
// global_load_dwordx4, 256 B contiguous per quad, L2-resident.
// ---------------------------------------------------------------------------

// Prepass transpose: LDS tiled [t][s], pitch 136 u16 (16B-aligned rows),
// s-chunk XOR swizzle so the read side is ds_read_b128 (2-way = free).
__device__ __forceinline__ void transpose_block_c(const float* __restrict__ src,
                                                  unsigned short* __restrict__ dst,
                                                  unsigned short* lds) {
  const int tid = threadIdx.x;
  const float4* s4 = (const float4*)src;
#pragma unroll
  for (int it = 0; it < 16; ++it) {
    int i4 = tid + it * 256;
    float4 v = s4[i4];
    int s = i4 >> 5;
    int t0 = (i4 * 4) & 127;
    int sc = s >> 3, se = s & 7;
#pragma unroll
    for (int e = 0; e < 4; ++e) {
      int t = t0 + e;
      lds[t * 136 + ((sc ^ ((t >> 2) & 7)) << 3) + se] = f2bf(((const float*)&v)[e]);
    }
  }
  __syncthreads();
#pragma unroll
  for (int it = 0; it < 8; ++it) {
    int c = tid + it * 256;
    int tr = c >> 4, sc = c & 15;
    uint4 d = *(const uint4*)(lds + tr * 136 + ((sc ^ ((tr >> 2) & 7)) << 3));
    *(uint4*)(dst + (sc * 128 + tr) * 8) = d;
  }
}

__global__ __launch_bounds__(256) void prepass_kernel(
    const float* __restrict__ W1, const float* __restrict__ trend2,
    const float* __restrict__ Wm1, const float* __restrict__ Wm2,
    unsigned short* __restrict__ W1Tc, unsigned short* __restrict__ T2c,
    unsigned short* __restrict__ Wm1c, unsigned short* __restrict__ Wm2c,
    float* __restrict__ out2) {
  __shared__ unsigned short lds[128 * 136];
  const int bid = blockIdx.x;
  if (bid < 256) {               // W1[i][j][s][t] -> chunks (kq_s, t)
    transpose_block_c(W1 + bid * 16384, W1Tc + bid * 16384, lds);
  } else if (bid < 288) {        // trend2[b][s][h] -> chunks (kq_s, h)
    const int b = bid - 256;
    transpose_block_c(trend2 + b * 16384, T2c + b * 16384, lds);
    const float4* s4 = (const float4*)(trend2 + b * 16384);
    float4* d4 = (float4*)(out2 + b * 16384);
#pragma unroll
    for (int it = 0; it < 16; ++it)
      d4[threadIdx.x + it * 256] = s4[threadIdx.x + it * 256];
  } else if (bid == 288) {       // Wm[in][out] -> chunks (kq_in, out)
    transpose_block_c(Wm1, Wm1c, lds);
  } else {
    transpose_block_c(Wm2, Wm2c, lds);
  }
}

// ---------------------------------------------------------------------------
// Mix kernel v3: block = (jg of 4 consecutive j, b); grid 1024 = 4 blocks/CU.
// M = t (A = W1Tc[j], per-j), N = h (B = XTc[b], SHARED across the 4 j's:
// each B fragment feeds 16 MFMAs). ntiles/ksteps uniform within a jg group.
// Passes p over h-halves (acc 64 VGPR), phases q over m-tile {wave, wave+4}.
// Epilogue gelu is sigmoid-form folded to 6 VALU/elem:
//   psum += (a*w2 + b1*w2) * rcp(1 + exp2(-2.4555*(a + b1)))
// ---------------------------------------------------------------------------
__global__ __launch_bounds__(256, 4) void mix_kernel(
    const unsigned short* __restrict__ XTc,   // [32] chunks (kq_s, h)
    const unsigned short* __restrict__ W1Tc,  // [128] chunks (kq_s, t), this stage
    const float* __restrict__ b1,             // [128][128] (j, t)
    const float* __restrict__ W2,             // [128][128] (j, t)
    const float* __restrict__ b2,             // [128]
    const float* __restrict__ trend,          // [32][128][128] fp32
    unsigned short* __restrict__ xoutc) {     // [32] chunks (kq_h, j)
  __shared__ float res_ws[4][4][64];
  const int bid = blockIdx.x;
  const int jg = bid >> 5;   // consecutive bids share W1Tc[jg] in L2
  const int b = bid & 31;
  const int j0 = jg * 4;
  const int tid = threadIdx.x;
  const int wave = tid >> 6;
  const int lane = tid & 63;
  const int lane15 = lane & 15;
  const int quad = lane >> 4;

  const int ntiles = (j0 >> 4) + 1;  // t-tiles with t <= j (uniform in group)
  const int ksteps = (j0 >> 5) + 1;  // k 32-steps with s <= j

  const unsigned short* Bb = XTc + b * 16384;
  const unsigned short* A0 = W1Tc + j0 * 16384;
  const float C = -2.45546937f;  // -1.702 * log2(e)

#pragma unroll
  for (int p = 0; p < 2; ++p) {
    float psum[4][4];
#pragma unroll
    for (int jj = 0; jj < 4; ++jj)
#pragma unroll
      for (int ni = 0; ni < 4; ++ni) psum[jj][ni] = 0.f;

#pragma unroll
    for (int q = 0; q < 2; ++q) {
      const int mt = wave + q * 4;
      if (mt < ntiles) {
        f32x4 acc[4][4];
#pragma unroll
        for (int jj = 0; jj < 4; ++jj)
#pragma unroll
          for (int ni = 0; ni < 4; ++ni) {
            f32x4 z = {0.f, 0.f, 0.f, 0.f};
            acc[jj][ni] = z;
          }
        for (int ks = 0; ks < ksteps; ++ks) {
          const int kq = ks * 4 + quad;
          const unsigned short* bp = Bb + (kq * 128 + p * 64 + lane15) * 8;
          bf16x8 bf0 = *(const bf16x8*)(bp);
          bf16x8 bf1 = *(const bf16x8*)(bp + 128);
          bf16x8 bf2 = *(const bf16x8*)(bp + 256);
          bf16x8 bf3 = *(const bf16x8*)(bp + 384);
#pragma unroll
          for (int jj = 0; jj < 4; ++jj) {
            bf16x8 a = *(const bf16x8*)(A0 + jj * 16384 +
                                        (kq * 128 + mt * 16 + lane15) * 8);
            acc[jj][0] = __builtin_amdgcn_mfma_f32_16x16x32_bf16(a, bf0, acc[jj][0], 0, 0, 0);
            acc[jj][1] = __builtin_amdgcn_mfma_f32_16x16x32_bf16(a, bf1, acc[jj][1], 0, 0, 0);
            acc[jj][2] = __builtin_amdgcn_mfma_f32_16x16x32_bf16(a, bf2, acc[jj][2], 0, 0, 0);
            acc[jj][3] = __builtin_amdgcn_mfma_f32_16x16x32_bf16(a, bf3, acc[jj][3], 0, 0, 0);
          }
        }
        const int tb = mt * 16 + quad * 4;
#pragma unroll
        for (int jj = 0; jj < 4; ++jj) {
          const int j = j0 + jj;
          float4 b1v = *(const float4*)(b1 + j * 128 + tb);
          float4 w2v = *(const float4*)(W2 + j * 128 + tb);
#pragma unroll
          for (int r = 0; r < 4; ++r) {
            float b1r = ((const float*)&b1v)[r];
            float w2r = ((const float*)&w2v)[r];
            float cb = C * b1r;
            float bw = b1r * w2r;
#pragma unroll
            for (int ni = 0; ni < 4; ++ni) {
              float a = acc[jj][ni][r];
              float m = __builtin_fmaf(a, C, cb);
              float e = fast_exp2(m);
              float rr = fast_rcp(1.0f + e);
              float yw = __builtin_fmaf(a, w2r, bw);
              psum[jj][ni] = __builtin_fmaf(yw, rr, psum[jj][ni]);
            }
          }
        }
      }
    }
#pragma unroll
    for (int jj = 0; jj < 4; ++jj)
#pragma unroll
      for (int ni = 0; ni < 4; ++ni) {
        float v = psum[jj][ni];
        v += __shfl_xor(v, 16, 64);
        v += __shfl_xor(v, 32, 64);
        psum[jj][ni] = v;
      }
#pragma unroll
    for (int jj = 0; jj < 4; ++jj)
      res_ws[wave][jj][quad * 16 + lane15] = psum[jj][quad];
    __syncthreads();
    {
      const int jj = tid >> 6;
      const int hh = tid & 63;
      const int j = j0 + jj;
      const int h = p * 64 + hh;
      float v = res_ws[0][jj][hh] + res_ws[1][jj][hh] +
                res_ws[2][jj][hh] + res_ws[3][jj][hh] +
                b2[j] + trend[(b * 128 + j) * 128 + h];
      xoutc[b * 16384 + ((h >> 3) * 128 + j) * 8 + (h & 7)] = f2bf(v);
    }
    __syncthreads();
  }
}

// ---------------------------------------------------------------------------
// MLP kernel v3: grid 256 = 32 b x 8 tiles of 16 rows (full-CU coverage).
// Fragments direct from L2; LDS only for the GEMM1->GEMM2 bounce + transpose.
// ---------------------------------------------------------------------------
__global__ __launch_bounds__(256) void mlp_kernel(
    const unsigned short* __restrict__ Xc,    // [32] chunks (kq_h, j)
    const unsigned short* __restrict__ Wm1c,  // chunks (kq_in, out)
    const unsigned short* __restrict__ Wm2c,
    const float* __restrict__ bm1,
    const float* __restrict__ bm2,
    float* __restrict__ outf,                 // [32][128][128] fp32
    unsigned short* __restrict__ outTc,       // [32] chunks (kq_s, h), optional
    const int write_t) {
  __shared__ __align__(16) unsigned short U[16 * 128];  // chunks (kq_h, row16)
  __shared__ unsigned short ldsT[16 * 136];
  const int bid = blockIdx.x;
  const int b = bid >> 3;
  const int mb = bid & 7;
  const int tid = threadIdx.x;
  const int wave = tid >> 6;
  const int lane = tid & 63;
  const int lane15 = lane & 15;
  const int quad = lane >> 4;

  const unsigned short* Xb = Xc + b * 16384;

  f32x4 acc[2];
  { f32x4 z = {0.f, 0.f, 0.f, 0.f}; acc[0] = z; acc[1] = z; }
#pragma unroll
  for (int ks = 0; ks < 4; ++ks) {  // GEMM1: x @ Wm1
    int kq = ks * 4 + quad;
    bf16x8 a  = *(const bf16x8*)(Xb + (kq * 128 + mb * 16 + lane15) * 8);
    bf16x8 w0 = *(const bf16x8*)(Wm1c + (kq * 128 + wave * 32 + lane15) * 8);
    bf16x8 w1 = *(const bf16x8*)(Wm1c + (kq * 128 + wave * 32 + 16 + lane15) * 8);
    acc[0] = __builtin_amdgcn_mfma_f32_16x16x32_bf16(a, w0, acc[0], 0, 0, 0);
    acc[1] = __builtin_amdgcn_mfma_f32_16x16x32_bf16(a, w1, acc[1], 0, 0, 0);
  }
#pragma unroll
  for (int ni = 0; ni < 2; ++ni) {  // bias+gelu -> U (A-layout for GEMM2)
    int n = wave * 32 + ni * 16 + lane15;
    float bv = bm1[n];
#pragma unroll
    for (int r = 0; r < 4; ++r) {
      int jr = quad * 4 + r;
      U[((n >> 3) * 16 + jr) * 8 + (n & 7)] = f2bf(gelu_f(acc[ni][r] + bv));
    }
  }
  __syncthreads();
  { f32x4 z = {0.f, 0.f, 0.f, 0.f}; acc[0] = z; acc[1] = z; }
#pragma unroll
  for (int ks = 0; ks < 4; ++ks) {  // GEMM2: u @ Wm2
    int kq = ks * 4 + quad;
    bf16x8 a  = *(const bf16x8*)(U + (kq * 16 + lane15) * 8);
    bf16x8 w0 = *(const bf16x8*)(Wm2c + (kq * 128 + wave * 32 + lane15) * 8);
    bf16x8 w1 = *(const bf16x8*)(Wm2c + (kq * 128 + wave * 32 + 16 + lane15) * 8);
    acc[0] = __builtin_amdgcn_mfma_f32_16x16x32_bf16(a, w0, acc[0], 0, 0, 0);
    acc[1] = __builtin_amdgcn_mfma_f32_16x16x32_bf16(a, w1, acc[1], 0, 0, 0);
  }
  {
    float* outb = outf + b * 16384 + mb * 16 * 128;
#pragma unroll
    for (int ni = 0; ni < 2; ++ni) {
      int n = wave * 32 + ni * 16 + lane15;
      float bv = bm2[n];
#pragma unroll
      for (int r = 0; r < 4; ++r) {
        int jr = quad * 4 + r;
        float v = acc[ni][r] + bv;
        outb[jr * 128 + n] = v;
        if (write_t) ldsT[jr * 136 + n] = f2bf(v);
      }
    }
  }
  if (write_t) {  // emit chunks (kq_s, h) for the next mix stage's B-operand
    __syncthreads();
    int h = tid & 127, jr8 = tid >> 7;
    unsigned short tmp[8] __attribute__((aligned(16)));
#pragma unroll
    for (int e = 0; e < 8; ++e) tmp[e] = ldsT[(jr8 * 8 + e) * 136 + h];
    *(uint4*)(outTc + b * 16384 + ((mb * 2 + jr8) * 128 + h) * 8) = *(const uint4*)tmp;
  }
}

// ---------------------------------------------------------------------------
extern "C" void kernel_launch(void* const* d_in, const int* in_sizes, int n_in,
                              void* d_out, int out_size, void* d_ws, size_t ws_size,
                              hipStream_t stream) {
  (void)in_sizes; (void)n_in; (void)out_size; (void)ws_size;
  const float* trend0 = (const float*)d_in[0];
  const float* trend1 = (const float*)d_in[1];
  const float* trend2 = (const float*)d_in[2];
  const float* W1  = (const float*)d_in[3];
  const float* b1  = (const float*)d_in[4];
  const float* W2  = (const float*)d_in[5];
  const float* b2  = (const float*)d_in[6];
  const float* Wm1 = (const float*)d_in[7];
  const float* bm1 = (const float*)d_in[8];
  const float* Wm2 = (const float*)d_in[9];
  const float* bm2 = (const float*)d_in[10];
  float* out = (float*)d_out;
  char* ws = (char*)d_ws;

  unsigned short* W1Tc = (unsigned short*)(ws);             // 8 MB
  unsigned short* T2c  = (unsigned short*)(ws + 8388608);   // 1 MB
  unsigned short* x1c  = (unsigned short*)(ws + 9437184);   // 1 MB
  unsigned short* A1Tc = (unsigned short*)(ws + 10485760);  // 1 MB
  unsigned short* x2c  = (unsigned short*)(ws + 11534336);  // 1 MB
  unsigned short* Wm1c = (unsigned short*)(ws + 12582912);  // 32 KB
  unsigned short* Wm2c = (unsigned short*)(ws + 12615680);  // 32 KB

  // outputs: [A2 | A1 | trend2]
  prepass_kernel<<<290, 256, 0, stream>>>(W1, trend2, Wm1, Wm2,
                                          W1Tc, T2c, Wm1c, Wm2c, out + 2 * BSH);
  // stage i=0: X = trend2, residual = trend1
  mix_kernel<<<1024, 256, 0, stream>>>(T2c, W1Tc, b1, W2, b2, trend1, x1c);
  // A1 = mlp(x1) -> d_out[1] (+ chunked transpose for next mix stage)
  mlp_kernel<<<256, 256, 0, stream>>>(x1c, Wm1c, Wm2c, bm1, bm2,
                                      out + BSH, A1Tc, 1);
  // stage i=1: X = A1, residual = trend0
  mix_kernel<<<1024, 256, 0, stream>>>(A1Tc, W1Tc + 128 * 16384, b1 + 16384,
                                       W2 + 16384, b2 + 128, trend0, x2c);
  // A2 = mlp(x2) -> d_out[0]
  mlp_kernel<<<256, 256, 0, stream>>>(x2c, Wm1c, Wm2c, bm1, bm2,
                                      out, (unsigned short*)nullptr, 0);
}

// Round 4
// 145.814 us; speedup vs baseline: 1.6662x; 1.0048x over previous
//
#include <hip/hip_runtime.h>
#include <stdint.h>

#define BSH (32 * 128 * 128)

typedef __attribute__((ext_vector_type(8))) __bf16 bf16x8;
typedef __attribute__((ext_vector_type(4))) float f32x4;

__device__ __forceinline__ unsigned short f2bf(float f) {
  union { float f; unsigned u; } v; v.f = f;
  return (unsigned short)((v.u + 0x7FFFu + ((v.u >> 16) & 1u)) >> 16);
}

__device__ __forceinline__ float fast_exp2(float x) {
#if __has_builtin(__builtin_amdgcn_exp2f)
  return __builtin_amdgcn_exp2f(x);
#else
  float r; asm("v_exp_f32 %0, %1" : "=v"(r) : "v"(x)); return r;
#endif
}
__device__ __forceinline__ float fast_rcp(float x) {
#if __has_builtin(__builtin_amdgcn_rcpf)
  return __builtin_amdgcn_rcpf(x);
#else
  float r; asm("v_rcp_f32 %0, %1" : "=v"(r) : "v"(x)); return r;
#endif
}

// tanh-form GELU (MLP path; ~3e-3 max err vs exact erf GELU).
__device__ __forceinline__ float gelu_f(float y) {
  float u = y * y;
  float p = __builtin_fmaf(u, 0.044715f, 1.0f) * y;
  float w = fast_exp2(p * 2.30220787f);
  return y - y * fast_rcp(1.0f + w);
}

// XCD-pinned jg schedule: assuming round-robin bid->XCD (bid&7), XCD x owns
// jg in {x, 15-x, 16+x, 31-x} (balanced: sum nt*ks ~= 55 per XCD). Keeps the
// per-XCD working set (16 j-blocks of W1Tc + all XTc) ~1.6 MB < 4 MB L2.
__device__ __forceinline__ int jg_of(int x, int cls) {
  return cls == 0 ? x : cls == 1 ? 15 - x : cls == 2 ? 16 + x : 31 - x;
}

// ---------------------------------------------------------------------------
// Chunked k-major layout: tensor [row][k] stored as chunk(kq,row) =
// base + (kq*128 + row)*8 bf16 (16 B). MFMA fragment read = one
// global_load_dwordx4, 256 B contiguous per quad.
// ---------------------------------------------------------------------------
__device__ __forceinline__ void transpose_block_c(const float* __restrict__ src,
                                                  unsigned short* __restrict__ dst,
                                                  unsigned short* lds) {
  const int tid = threadIdx.x;
  const float4* s4 = (const float4*)src;
#pragma unroll
  for (int it = 0; it < 16; ++it) {
    int i4 = tid + it * 256;
    float4 v = s4[i4];
    int s = i4 >> 5;
    int t0 = (i4 * 4) & 127;
    int sc = s >> 3, se = s & 7;
#pragma unroll
    for (int e = 0; e < 4; ++e) {
      int t = t0 + e;
      lds[t * 136 + ((sc ^ ((t >> 2) & 7)) << 3) + se] = f2bf(((const float*)&v)[e]);
    }
  }
  __syncthreads();
#pragma unroll
  for (int it = 0; it < 8; ++it) {
    int c = tid + it * 256;
    int tr = c >> 4, sc = c & 15;
    uint4 d = *(const uint4*)(lds + tr * 136 + ((sc ^ ((tr >> 2) & 7)) << 3));
    *(uint4*)(dst + (sc * 128 + tr) * 8) = d;
  }
}

__global__ __launch_bounds__(256) void prepass_kernel(
    const float* __restrict__ W1, const float* __restrict__ trend2,
    const float* __restrict__ Wm1, const float* __restrict__ Wm2,
    unsigned short* __restrict__ W1Tc, unsigned short* __restrict__ T2c,
    unsigned short* __restrict__ Wm1c, unsigned short* __restrict__ Wm2c,
    float* __restrict__ out2) {
  __shared__ unsigned short lds[128 * 136];
  const int bid = blockIdx.x;
  if (bid < 256) {  // W1[stage][j][s][t] -> chunks (kq_s, t), XCD-pinned j map
    int x = bid & 7, r = bid >> 3;
    int stage = r >> 4, rr = r & 15;
    int j = jg_of(x, rr >> 2) * 4 + (rr & 3);
    int blk = stage * 128 + j;
    transpose_block_c(W1 + blk * 16384, W1Tc + blk * 16384, lds);
  } else if (bid < 288) {  // trend2[b][s][h] -> chunks (kq_s, h) + fp32 copy
    const int b = bid - 256;
    transpose_block_c(trend2 + b * 16384, T2c + b * 16384, lds);
    const float4* s4 = (const float4*)(trend2 + b * 16384);
    float4* d4 = (float4*)(out2 + b * 16384);
#pragma unroll
    for (int it = 0; it < 16; ++it)
      d4[threadIdx.x + it * 256] = s4[threadIdx.x + it * 256];
  } else if (bid == 288) {
    transpose_block_c(Wm1, Wm1c, lds);
  } else {
    transpose_block_c(Wm2, Wm2c, lds);
  }
}

// ---------------------------------------------------------------------------
// Fused mix+MLP: block = (jg of 4 j, b), grid 1024, XCD-pinned jg.
// Phase 1 (mix): Y = W1[j] x X^T (M=t, N=h, K=s, triangular-skipped);
//   res[h] = sum_t sigmoid-gelu(Y+b1)*W2; x[j,h] = res + b2 + trend -> LDS
//   bf16 A-tile xa (rows 0-3 = the block's 4 j, rows 4-15 zero).
// Phase 2 (MLP, per block's 4 rows): A2 = gelu(x@Wm1+bm1)@Wm2+bm2 via
//   16x16x32 MFMA on the padded 16-row tile; fp32 out + optional chunked
//   bf16 (next stage's B operand, 8B half-chunk per jg-parity).
// ---------------------------------------------------------------------------
__global__ __launch_bounds__(256, 4) void mix_fused_kernel(
    const unsigned short* __restrict__ XTc,   // [32] chunks (kq_s, h)
    const unsigned short* __restrict__ W1Tj,  // [128] chunks (kq_s, t), stage
    const float* __restrict__ b1j,            // [128][128] (j, t)
    const float* __restrict__ W2j,            // [128][128] (j, t)
    const float* __restrict__ b2j,            // [128]
    const float* __restrict__ trendR,         // [32][128][128] fp32 residual
    const unsigned short* __restrict__ Wm1c,  // chunks (kq_in, out)
    const unsigned short* __restrict__ Wm2c,
    const float* __restrict__ bm1,
    const float* __restrict__ bm2,
    float* __restrict__ outF,                 // [32][128][128] fp32 (MLP out)
    unsigned short* __restrict__ outTc,       // [32] chunks (kq_s, h) or null
    const int write_t) {
  __shared__ float res_ws[4][4][64];
  __shared__ __align__(16) unsigned short xa[16 * 128];  // MLP A-tile chunks
  __shared__ __align__(16) unsigned short U[16 * 128];   // GEMM1->2 bounce
  const int bid = blockIdx.x;
  const int x = bid & 7;
  const int i = bid >> 3;
  const int b = i & 31;
  const int jg = jg_of(x, i >> 5);
  const int j0 = jg * 4;
  const int tid = threadIdx.x;
  const int wave = tid >> 6;
  const int lane = tid & 63;
  const int lane15 = lane & 15;
  const int quad = lane >> 4;

  {  // zero the padded tiles (rows 4-15 must be 0 for the MFMA MLP)
    uint4 z = {0, 0, 0, 0};
    ((uint4*)xa)[tid] = z;
    ((uint4*)U)[tid] = z;
  }

  const int ntiles = (j0 >> 4) + 1;  // t-tiles with t <= j
  const int ksteps = (j0 >> 5) + 1;  // k 32-steps with s <= j
  const unsigned short* Bb = XTc + b * 16384;
  const unsigned short* A0 = W1Tj + j0 * 16384;
  const float C = -2.45546937f;  // -1.702 * log2(e)

#pragma unroll
  for (int p = 0; p < 2; ++p) {
    float psum[4][4];
#pragma unroll
    for (int jj = 0; jj < 4; ++jj)
#pragma unroll
      for (int ni = 0; ni < 4; ++ni) psum[jj][ni] = 0.f;

#pragma unroll
    for (int q = 0; q < 2; ++q) {
      const int mt = wave + q * 4;
      if (mt < ntiles) {
        f32x4 acc[4][4];
#pragma unroll
        for (int jj = 0; jj < 4; ++jj)
#pragma unroll
          for (int ni = 0; ni < 4; ++ni) {
            f32x4 z = {0.f, 0.f, 0.f, 0.f};
            acc[jj][ni] = z;
          }
        for (int ks = 0; ks < ksteps; ++ks) {
          const int kq = ks * 4 + quad;
          const unsigned short* bp = Bb + (kq * 128 + p * 64 + lane15) * 8;
          bf16x8 bfr[4], af[4];
#pragma unroll
          for (int ni = 0; ni < 4; ++ni)
            bfr[ni] = *(const bf16x8*)(bp + ni * 128);
#pragma unroll
          for (int jj = 0; jj < 4; ++jj)
            af[jj] = *(const bf16x8*)(A0 + jj * 16384 +
                                      (kq * 128 + mt * 16 + lane15) * 8);
#pragma unroll
          for (int jj = 0; jj < 4; ++jj)
#pragma unroll
            for (int ni = 0; ni < 4; ++ni)
              acc[jj][ni] = __builtin_amdgcn_mfma_f32_16x16x32_bf16(
                  af[jj], bfr[ni], acc[jj][ni], 0, 0, 0);
        }
        const int tb = mt * 16 + quad * 4;
#pragma unroll
        for (int jj = 0; jj < 4; ++jj) {
          const int j = j0 + jj;
          float4 b1v = *(const float4*)(b1j + j * 128 + tb);
          float4 w2v = *(const float4*)(W2j + j * 128 + tb);
#pragma unroll
          for (int r = 0; r < 4; ++r) {
            float b1r = ((const float*)&b1v)[r];
            float w2r = ((const float*)&w2v)[r];
            float cb = C * b1r;
            float bw = b1r * w2r;
#pragma unroll
            for (int ni = 0; ni < 4; ++ni) {
              float a = acc[jj][ni][r];
              float m = __builtin_fmaf(a, C, cb);
              float e = fast_exp2(m);
              float rr2 = fast_rcp(1.0f + e);
              float yw = __builtin_fmaf(a, w2r, bw);
              psum[jj][ni] = __builtin_fmaf(yw, rr2, psum[jj][ni]);
            }
          }
        }
      }
    }
#pragma unroll
    for (int jj = 0; jj < 4; ++jj)
#pragma unroll
      for (int ni = 0; ni < 4; ++ni) {
        float v = psum[jj][ni];
        v += __shfl_xor(v, 16, 64);
        v += __shfl_xor(v, 32, 64);
        psum[jj][ni] = v;
      }
#pragma unroll
    for (int jj = 0; jj < 4; ++jj)
      res_ws[wave][jj][quad * 16 + lane15] = psum[jj][quad];
    __syncthreads();
    {  // combine + residual -> bf16 A-tile row jj, k=h chunks
      const int jj = tid >> 6;
      const int hh = tid & 63;
      const int j = j0 + jj;
      const int h = p * 64 + hh;
      float v = res_ws[0][jj][hh] + res_ws[1][jj][hh] +
                res_ws[2][jj][hh] + res_ws[3][jj][hh] +
                b2j[j] + trendR[(b * 128 + j) * 128 + h];
      xa[((h >> 3) * 16 + jj) * 8 + (h & 7)] = f2bf(v);
    }
    __syncthreads();
  }

  // ---- fused MLP on the block's 4 rows (16-row padded MFMA tile) ----
  f32x4 acc2[2];
  { f32x4 z = {0.f, 0.f, 0.f, 0.f}; acc2[0] = z; acc2[1] = z; }
#pragma unroll
  for (int ks = 0; ks < 4; ++ks) {  // GEMM1: x @ Wm1
    int kq = ks * 4 + quad;
    bf16x8 a = *(const bf16x8*)(xa + (kq * 16 + lane15) * 8);
    bf16x8 w0 = *(const bf16x8*)(Wm1c + (kq * 128 + (wave * 2 + 0) * 16 + lane15) * 8);
    bf16x8 w1 = *(const bf16x8*)(Wm1c + (kq * 128 + (wave * 2 + 1) * 16 + lane15) * 8);
    acc2[0] = __builtin_amdgcn_mfma_f32_16x16x32_bf16(a, w0, acc2[0], 0, 0, 0);
    acc2[1] = __builtin_amdgcn_mfma_f32_16x16x32_bf16(a, w1, acc2[1], 0, 0, 0);
  }
  if (quad == 0) {  // rows 0-3 live in quad 0; bias+gelu -> U A-tile
#pragma unroll
    for (int nt = 0; nt < 2; ++nt) {
      int o = (wave * 2 + nt) * 16 + lane15;
      float bv = bm1[o];
#pragma unroll
      for (int r = 0; r < 4; ++r) {
        float g = gelu_f(acc2[nt][r] + bv);
        U[((o >> 3) * 16 + r) * 8 + (o & 7)] = f2bf(g);
      }
    }
  }
  __syncthreads();
  { f32x4 z = {0.f, 0.f, 0.f, 0.f}; acc2[0] = z; acc2[1] = z; }
#pragma unroll
  for (int ks = 0; ks < 4; ++ks) {  // GEMM2: u @ Wm2
    int kq = ks * 4 + quad;
    bf16x8 a = *(const bf16x8*)(U + (kq * 16 + lane15) * 8);
    bf16x8 w0 = *(const bf16x8*)(Wm2c + (kq * 128 + (wave * 2 + 0) * 16 + lane15) * 8);
    bf16x8 w1 = *(const bf16x8*)(Wm2c + (kq * 128 + (wave * 2 + 1) * 16 + lane15) * 8);
    acc2[0] = __builtin_amdgcn_mfma_f32_16x16x32_bf16(a, w0, acc2[0], 0, 0, 0);
    acc2[1] = __builtin_amdgcn_mfma_f32_16x16x32_bf16(a, w1, acc2[1], 0, 0, 0);
  }
  if (quad == 0) {  // epilogue: fp32 out + optional chunked bf16 half-chunks
#pragma unroll
    for (int nt = 0; nt < 2; ++nt) {
      int o = (wave * 2 + nt) * 16 + lane15;
      float bv = bm2[o];
      unsigned short tmp4[4] __attribute__((aligned(8)));
#pragma unroll
      for (int r = 0; r < 4; ++r) {
        float v = acc2[nt][r] + bv;
        outF[b * 16384 + (j0 + r) * 128 + o] = v;
        tmp4[r] = f2bf(v);
      }
      if (write_t)
        *(uint2*)(outTc + b * 16384 + ((j0 >> 3) * 128 + o) * 8 + (j0 & 7)) =
            *(const uint2*)tmp4;
    }
  }
}

// ---------------------------------------------------------------------------
extern "C" void kernel_launch(void* const* d_in, const int* in_sizes, int n_in,
                              void* d_out, int out_size, void* d_ws, size_t ws_size,
                              hipStream_t stream) {
  (void)in_sizes; (void)n_in; (void)out_size; (void)ws_size;
  const float* trend0 = (const float*)d_in[0];
  const float* trend1 = (const float*)d_in[1];
  const float* trend2 = (const float*)d_in[2];
  const float* W1  = (const float*)d_in[3];
  const float* b1  = (const float*)d_in[4];
  const float* W2  = (const float*)d_in[5];
  const float* b2  = (const float*)d_in[6];
  const float* Wm1 = (const float*)d_in[7];
  const float* bm1 = (const float*)d_in[8];
  const float* Wm2 = (const float*)d_in[9];
  const float* bm2 = (const float*)d_in[10];
  float* out = (float*)d_out;
  char* ws = (char*)d_ws;

  unsigned short* W1Tc = (unsigned short*)(ws);             // 8.39 MB (2 stages)
  unsigned short* T2c  = (unsigned short*)(ws + 8388608);   // 1 MB
  unsigned short* A1Tc = (unsigned short*)(ws + 9437184);   // 1 MB
  unsigned short* Wm1c = (unsigned short*)(ws + 10485760);  // 32 KB
  unsigned short* Wm2c = (unsigned short*)(ws + 10518528);  // 32 KB

  // outputs: [A2 | A1 | trend2]
  prepass_kernel<<<290, 256, 0, stream>>>(W1, trend2, Wm1, Wm2,
                                          W1Tc, T2c, Wm1c, Wm2c, out + 2 * BSH);
  // stage 0: X = trend2, residual = trend1 -> A1 (d_out[1]) + A1Tc chunks
  mix_fused_kernel<<<1024, 256, 0, stream>>>(
      T2c, W1Tc, b1, W2, b2, trend1, Wm1c, Wm2c, bm1, bm2,
      out + BSH, A1Tc, 1);
  // stage 1: X = A1, residual = trend0 -> A2 (d_out[0])
  mix_fused_kernel<<<1024, 256, 0, stream>>>(
      A1Tc, W1Tc + 128 * 16384, b1 + 16384, W2 + 16384, b2 + 128, trend0,
      Wm1c, Wm2c, bm1, bm2, out, (unsigned short*)nullptr, 0);
}